// Round 11
// baseline (2311.942 us; speedup 1.0000x reference)
//
#include <hip/hip_runtime.h>
#include <hip/hip_fp16.h>
#include <math.h>

#define Tt 64
#define Bb 16
#define Nn 256
#define Ww 64
#define Rr 4
#define INd 64
#define OUTd 64
#define IFS 471
#define EPSf 1e-6f

// packed half2 weight layout: quad-of-k2 per column, wave-coalesced.
#define W1OFF   0        // K2=160, Ncol=256 -> 40960
#define W2OFF   40960    // K2=128, Ncol=256 -> 32768
#define WIFOFF  73728    // K2=128, Ncol=471 -> 60288
#define WOUTOFF 134016   // K2=128, Ncol=64  -> 8192
#define WMEMOFF 142208   // K2=128, Ncol=64  -> 8192
#define WTOT    150400

// link: 256 rows x 130 dwords (even row stride -> b64 row reads in P8)
#define LROW    130
#define LINKB   (256 * LROW * 4)     // 133120 B
#define SCRB    16384                // 4096 floats / 8192 halfs
#define FIXF    3456
#define SMEM_MAIN (LINKB + SCRB + FIXF * 4)   // 163328 <= 163840
#define SMEM_FB   (SCRB + FIXF * 4)

// s_rwh padded r-stride: 132 dwords (132%32=4 -> r-groups on disjoint banks)
#define RWS 132

typedef _Float16 h2v __attribute__((ext_vector_type(2)));
__device__ __forceinline__ float fdot2(__half2 a, __half2 b, float c) {
    return __builtin_amdgcn_fdot2(*(h2v*)&a, *(h2v*)&b, c, false);
}
__device__ __forceinline__ __half2 pkh(float a, float b) {
    auto r = __builtin_amdgcn_cvt_pkrtz(a, b);   // __fp16 ext_vector(2)
    return *(__half2*)&r;
}

__device__ __forceinline__ float rcpf(float x) {
#if __has_builtin(__builtin_amdgcn_rcpf)
    return __builtin_amdgcn_rcpf(x);
#else
    return 1.f / x;
#endif
}
// fast sigmoid/tanh via native v_exp + v_rcp (~1e-6 rel err, << fp16 pipeline noise)
__device__ __forceinline__ float sigm(float x) { return rcpf(1.f + __expf(-x)); }
__device__ __forceinline__ float tanh_fast(float x) {
    float xc = fminf(fmaxf(x, -15.f), 15.f);
    float e = __expf(2.f * xc);
    return (e - 1.f) * rcpf(e + 1.f);
}
__device__ __forceinline__ float oneplus_(float x) {
    return 1.f + fmaxf(x, 0.f) + log1pf(expf(-fabsf(x)));
}
__device__ __forceinline__ float wsum(float v) {
#pragma unroll
    for (int o = 32; o; o >>= 1) v += __shfl_xor(v, o, 64);
    return v;
}
__device__ __forceinline__ float wmaxr(float v) {
#pragma unroll
    for (int o = 32; o; o >>= 1) v = fmaxf(v, __shfl_xor(v, o, 64));
    return v;
}

// shared GEMV-partial body (R8 version: depth-1 rotation, proven 64 VGPR / no
// spill / best steady 1612). wP = column base (wp + OFF + n*4), str = Ncol*4
// (half2 units per k8 block), iters in k2 units (multiple of 8, >= 16).
__device__ __attribute__((noinline)) float gemv_part(
    const __half2* __restrict__ wP, int str, int iters,
    const __half2* __restrict__ vin)
{
    float a[8] = {0.f,0.f,0.f,0.f,0.f,0.f,0.f,0.f};
    float4 h0 = *(const float4*)(wP);
    float4 h1 = *(const float4*)(wP + str);
#pragma unroll 1
    for (int j0 = 0; j0 < iters - 8; j0 += 8) {
        int k8n = (j0 >> 2) + 2;
        float4 n0 = *(const float4*)(wP + (size_t)k8n * str);
        float4 n1 = *(const float4*)(wP + (size_t)(k8n + 1) * str);
        float4 v0 = *(const float4*)(vin + j0);
        float4 v1 = *(const float4*)(vin + j0 + 4);
        const __half2* hh0 = (const __half2*)&h0;
        const __half2* hh1 = (const __half2*)&h1;
        const __half2* vv0 = (const __half2*)&v0;
        const __half2* vv1 = (const __half2*)&v1;
#pragma unroll
        for (int u = 0; u < 4; ++u) a[u]     = fdot2(hh0[u], vv0[u], a[u]);
#pragma unroll
        for (int u = 0; u < 4; ++u) a[4 + u] = fdot2(hh1[u], vv1[u], a[4 + u]);
        h0 = n0; h1 = n1;
    }
    {
        float4 v0 = *(const float4*)(vin + iters - 8);
        float4 v1 = *(const float4*)(vin + iters - 4);
        const __half2* hh0 = (const __half2*)&h0;
        const __half2* hh1 = (const __half2*)&h1;
        const __half2* vv0 = (const __half2*)&v0;
        const __half2* vv1 = (const __half2*)&v1;
#pragma unroll
        for (int u = 0; u < 4; ++u) a[u]     = fdot2(hh0[u], vv0[u], a[u]);
#pragma unroll
        for (int u = 0; u < 4; ++u) a[4 + u] = fdot2(hh1[u], vv1[u], a[4 + u]);
    }
    return ((a[0]+a[1])+(a[2]+a[3])) + ((a[4]+a[5])+(a[6]+a[7]));
}

// ---- converter: fp32 weights -> packed half2 quad layout ----
__global__ void convert_weights(const float* __restrict__ W1, const float* __restrict__ W2,
                                const float* __restrict__ Wif, const float* __restrict__ Wout,
                                const float* __restrict__ Wmem, __half2* __restrict__ wp) {
    int i = blockIdx.x * blockDim.x + threadIdx.x;
    if (i >= WTOT) return;
    float a, b;
    if (i < W2OFF) {
        int q = i & 3, s = i >> 2, n = s & 255, k2 = (s >> 8) * 4 + q;
        a = W1[(2*k2)*256+n];  b = W1[(2*k2+1)*256+n];
    } else if (i < WIFOFF) {
        int t = i - W2OFF;
        int q = t & 3, s = t >> 2, n = s & 255, k2 = (s >> 8) * 4 + q;
        a = W2[(2*k2)*256+n];  b = W2[(2*k2+1)*256+n];
    } else if (i < WOUTOFF) {
        int t = i - WIFOFF;
        int q = t & 3, s = t >> 2, o = s % IFS, k2 = (s / IFS) * 4 + q;
        a = Wif[(2*k2)*IFS+o]; b = Wif[(2*k2+1)*IFS+o];
    } else if (i < WMEMOFF) {
        int t = i - WOUTOFF;
        int q = t & 3, s = t >> 2, n = s & 63, k2 = (s >> 6) * 4 + q;
        a = Wout[(2*k2)*64+n]; b = Wout[(2*k2+1)*64+n];
    } else {
        int t = i - WMEMOFF;
        int q = t & 3, s = t >> 2, n = s & 63, k2 = (s >> 6) * 4 + q;
        a = Wmem[(2*k2)*64+n]; b = Wmem[(2*k2+1)*64+n];
    }
    wp[i] = __floats2half2_rn(a, b);
}

template <bool LLINK>
__global__ __launch_bounds__(1024) void dnc_kernel(
    const float* __restrict__ x, const float* __restrict__ b1,
    const float* __restrict__ b2, const float* __restrict__ bif,
    const __half2* __restrict__ wp,
    __half* __restrict__ memg,      // per batch 64*256 halves, [w][n]
    __half2* __restrict__ memWg,    // per batch 32*256 dwords, [w2][n]
    __half2* __restrict__ linkg,    // fallback link
    float* __restrict__ out)
{
    extern __shared__ __align__(16) char smem[];
    const int b = blockIdx.x;
    const int tid = threadIdx.x;
    const int lane = tid & 63;
    const int wv = tid >> 6;

    __half2* l2p = (__half2*)smem;
    __half2* gl2 = linkg + (size_t)b * (256 * LROW);
    float* scr   = (float*)(smem + (LLINK ? LINKB : 0));
    __half* scrh = (__half*)scr;
    float* fx    = (float*)((char*)scr + SCRB);

    float*   s_rw    = fx + 0;                    // 1024 [n][r] fp32
    __half2* s_ctrlh = (__half2*)(fx + 1024);     // 160
    __half2* s_hh    = (__half2*)(fx + 1184);     // 128
    __half2* s_nnh   = (__half2*)(fx + 1312);     // 128
    __half2* s_rwh   = (__half2*)(fx + 1440);     // 528 = [r][RWS n-pairs]
    float* s_z     = fx + 1968;   // 472
    float* s_usage = fx + 2440;   // 256
    float* s_ww    = fx + 2696;   // 256
    float* s_prec  = fx + 2952;   // 256
    float* s_knorm = fx + 3208;   // 4
    float* s_rstr  = fx + 3212;   // 4
    float* s_rmode = fx + 3216;   // 12
    float* s_sc    = fx + 3228;   // 4
    float* s_red   = fx + 3232;   // 32 ([0]=lw, [8..12)=fg, [16..32)=rc sums)
    float* s_er    = fx + 3264;   // 64 (erase gates)
    __half2* s_keyh = (__half2*)(fx + 3328);      // 128 [r][32 w2] -> 3456 = FIXF
    float* s_srt   = scr + 1024;  // 256 (mega only, B8..B9)
    float* s_cp    = scr + 1280;  // 256 (mega only, B8..B9)
    __half2* s_keyw2 = (__half2*)(scr + 1280);    // 32 write-key pairs (B6..B7)
    float* s_wcdot = scr + 1536;  // 256 (B7..B9)
    float* s_wcss  = scr + 1792;  // 256 (B7..B9)
    __half2* s_wwh2 = (__half2*)(scr + 2048);     // 256 dup (ww,ww)   (B9..B10)
    __half2* s_tmh2 = (__half2*)(scr + 2304);     // 256 dup (1-ww,1-ww)
    unsigned* s_keyu = (unsigned*)(scr + 2560);   // 256 u64 rank keys (B7..B8)

    __half*  memh  = memg + (size_t)b * (Ww * Nn);
    __half2* memh2 = (__half2*)memh;
    __half2* memW2 = memWg + (size_t)b * (32 * 256);
    __half*  memWh = (__half*)memW2;

    auto lread = [&](int idx) -> __half2 {
        if constexpr (LLINK) return l2p[idx]; else return gl2[idx];
    };
    auto lwrite = [&](int idx, __half2 v) {
        if constexpr (LLINK) l2p[idx] = v; else gl2[idx] = v;
    };
    auto lread2 = [&](int idx) -> float2 {   // idx even: half2[idx], half2[idx+1]
        if constexpr (LLINK) return *(const float2*)(l2p + idx);
        else return *(const float2*)(gl2 + idx);
    };

    // ---- init (ws/LDS poisoned before every launch) ----
    {
        __half2 z2 = pkh(0.f, 0.f);
#pragma unroll 1
        for (int i = tid; i < 256 * LROW; i += 1024) lwrite(i, z2);
        __half2 e2 = __floats2half2_rn(EPSf, EPSf);
#pragma unroll 1
        for (int j = 0; j < 8; ++j) { memh2[tid + j * 1024] = e2; memW2[tid + j * 1024] = e2; }
        if (tid < 528) s_rwh[tid] = z2;
        if (tid < 32) {
            float2 xv = *(const float2*)&x[b * INd + 2 * tid];
            s_ctrlh[tid] = pkh(xv.x, xv.y);
        } else if (tid < 160) s_ctrlh[tid] = z2;
    }
    if (tid < 256) {
        s_usage[tid] = 0.f; s_ww[tid] = 0.f; s_prec[tid] = 0.f;
        s_rw[tid*4+0] = 0.f; s_rw[tid*4+1] = 0.f; s_rw[tid*4+2] = 0.f; s_rw[tid*4+3] = 0.f;
    }
    __syncthreads();   // entry barrier (loop-top barrier removed)

#pragma unroll 1
    for (int t = 0; t < Tt; ++t) {
        // ---- P1: GEMV1, in-wave reduce + tanh -> s_hh ----
        {
            int o = (wv << 4) + (lane & 15), kc = lane >> 4;
            float a = gemv_part(wp + W1OFF + o * 4 + kc * 10240, 1024, 40,
                                s_ctrlh + kc * 40);
            a += __shfl_xor(a, 16, 64);
            a += __shfl_xor(a, 32, 64);
            if (lane < 16) {
                float v = tanh_fast(b1[o] + a);
                float pv = __shfl_xor(v, 1, 64);
                if ((lane & 1) == 0) s_hh[o >> 1] = pkh(v, pv);
            }
        }
        __syncthreads();  // B2

        // ---- P2: GEMV2, in-wave reduce + tanh -> s_nnh ----
        {
            int o = (wv << 4) + (lane & 15), kc = lane >> 4;
            float a = gemv_part(wp + W2OFF + o * 4 + kc * 8192, 1024, 32,
                                s_hh + kc * 32);
            a += __shfl_xor(a, 16, 64);
            a += __shfl_xor(a, 32, 64);
            if (lane < 16) {
                float v = tanh_fast(b2[o] + a);
                float pv = __shfl_xor(v, 1, 64);
                if ((lane & 1) == 0) s_nnh[o >> 1] = pkh(v, pv);
            }
        }
        __syncthreads();  // B4

        // ---- P3: GEMV3, in-wave reduce -> s_z + packed keys + free gates ----
        {
            int o = (wv << 5) + (lane & 31);
            int kc = lane >> 5;
            float a = 0.f;
            if (o < IFS)
                a = gemv_part(wp + WIFOFF + o * 4 + kc * 30144, 1884, 64,
                              s_nnh + kc * 64);
            a += __shfl_xor(a, 32, 64);
            if (lane < 32 && o < IFS) {
                float v = bif[o] + a;
                s_z[o] = v;
                float pv1 = __shfl_xor(v, 1, 64);
                float pv4 = __shfl_xor(v, 4, 64);
                if (o < 256) {
                    if ((o & 4) == 0)           // w even
                        s_keyh[(o & 3) * 32 + (o >> 3)] = pkh(v, pv4);
                } else if (o >= 260 && o < 324) {
                    if ((o & 1) == 0)
                        s_keyw2[(o - 260) >> 1] = pkh(v, pv1);
                } else if (o >= 453 && o < 457) {
                    s_red[8 + (o - 453)] = sigm(v);   // free gates, once
                }
            }
        }
        __syncthreads();  // B6

        // ---- P4: scalars + usage/keys + wc dot/ss (merged wave roles) ----
        if (wv < 4) {
            float vz = s_z[lane * 4 + wv];
            float s = wsum(vz * vz);
            if (lane == 0) s_knorm[wv] = sqrtf(s) + EPSf;
        } else if (wv == 4) {
            float vz = s_z[260 + lane];
            float s = wsum(vz * vz);
            if (lane == 0) s_sc[3] = sqrtf(s) + EPSf;
        } else if (wv == 5) {
            if (lane < 4) s_rstr[lane] = oneplus_(s_z[256 + lane]);
            else if (lane >= 8 && lane < 12) {
                int r = lane - 8;
                float a = s_z[459+r], bm = s_z[463+r], c = s_z[467+r];
                float mx = fmaxf(a, fmaxf(bm, c));
                float ea = __expf(a-mx), eb = __expf(bm-mx), ec = __expf(c-mx);
                float inv = rcpf((ea+eb)+ec);
                s_rmode[0*4+r] = ea*inv; s_rmode[1*4+r] = eb*inv; s_rmode[2*4+r] = ec*inv;
            } else if (lane == 16) s_sc[0] = oneplus_(s_z[324]);
            else if (lane == 17) s_sc[1] = sigm(s_z[457]);
            else if (lane == 18) s_sc[2] = sigm(s_z[458]);
        } else if (wv == 6) {
            s_er[lane] = sigm(s_z[325 + lane]);   // erase gates, once per step
        } else if (wv >= 8 && wv < 12) {
            int n = tid - 512;
            float4 rw4 = *(const float4*)&s_rw[n*4];
            float4 fg4 = *(const float4*)&s_red[8];
            float ret = (1.f - fg4.x*rw4.x) * (1.f - fg4.y*rw4.y)
                      * (1.f - fg4.z*rw4.z) * (1.f - fg4.w*rw4.w);
            float u = s_usage[n], wwo = s_ww[n];
            float unew = (u + wwo - u * wwo) * ret;
            s_usage[n] = unew;
            // u64 sort key: usage>=0 -> IEEE bits order-monotonic; key = bits*256 + n
            unsigned ub = __float_as_uint(unew);
            s_keyu[2*n]     = (ub << 8) | (unsigned)n;
            s_keyu[2*n + 1] = ub >> 24;
        } else if (wv >= 12) {
            // wc dot/ss via memW; all 32 column loads issued up-front (latency batch)
            int n = tid - 768;
            const __half2* mW = memW2 + n;
            __half2 mva[16], mvb[16];
#pragma unroll
            for (int u = 0; u < 16; ++u) mva[u] = mW[u * 256];
#pragma unroll
            for (int u = 0; u < 16; ++u) mvb[u] = mW[(16 + u) * 256];
            float dot = 0.f, ssv = 0.f;
            {
                __half2 kv[16];
                *(float4*)&kv[0]  = *(const float4*)(s_keyw2);
                *(float4*)&kv[4]  = *(const float4*)(s_keyw2 + 4);
                *(float4*)&kv[8]  = *(const float4*)(s_keyw2 + 8);
                *(float4*)&kv[12] = *(const float4*)(s_keyw2 + 12);
#pragma unroll
                for (int u = 0; u < 16; ++u) {
                    ssv = fdot2(mva[u], mva[u], ssv);
                    dot = fdot2(mva[u], kv[u], dot);
                }
            }
            {
                __half2 kv[16];
                *(float4*)&kv[0]  = *(const float4*)(s_keyw2 + 16);
                *(float4*)&kv[4]  = *(const float4*)(s_keyw2 + 20);
                *(float4*)&kv[8]  = *(const float4*)(s_keyw2 + 24);
                *(float4*)&kv[12] = *(const float4*)(s_keyw2 + 28);
#pragma unroll
                for (int u = 0; u < 16; ++u) {
                    ssv = fdot2(mvb[u], mvb[u], ssv);
                    dot = fdot2(mvb[u], kv[u], dot);
                }
            }
            s_wcdot[n] = dot; s_wcss[n] = ssv;
        }
        __syncthreads();  // B7

        // ---- P5: rank partials (u64 keys, broadcast b128 loads) ----
        {
            int q = tid >> 8, n = tid & 255;
            unsigned long long kn = *(const unsigned long long*)&s_keyu[2*n];
            int cnt = 0;
            const unsigned long long* kp = (const unsigned long long*)s_keyu;
            int j0 = q * 64;
#pragma unroll 8
            for (int j = j0; j < j0 + 64; j += 2) {
                ulonglong2 kk = *(const ulonglong2*)&kp[j];
                cnt += (kk.x < kn);
                cnt += (kk.y < kn);
            }
            scr[q * 256 + n] = (float)cnt;
        }
        __syncthreads();  // B8

        // ---- P6: mega (wave 0) ----
        if (wv == 0) {
            int rk[4]; float uu[4];
#pragma unroll
            for (int i = 0; i < 4; ++i) {
                int n = lane * 4 + i;
                float c = scr[n] + scr[256+n] + scr[512+n] + scr[768+n];
                rk[i] = (int)(c + 0.5f);
                uu[i] = s_usage[n];
                s_srt[rk[i]] = uu[i];
            }
            float4 vs = ((const float4*)s_srt)[lane];
            float p1 = vs.x * vs.y, p2 = p1 * vs.z, tot = p2 * vs.w;
            float incl = tot;
#pragma unroll
            for (int off = 1; off < 64; off <<= 1) {
                float tv = __shfl_up(incl, off, 64);
                if (lane >= off) incl *= tv;
            }
            float excl = __shfl_up(incl, 1, 64);
            if (lane == 0) excl = 1.f;
            float4 o4v; o4v.x = excl; o4v.y = excl*vs.x; o4v.z = excl*p1; o4v.w = excl*p2;
            ((float4*)s_cp)[lane] = o4v;

            float sims[4], mx = -1e30f;
#pragma unroll
            for (int i = 0; i < 4; ++i) {
                int n = lane * 4 + i;
                sims[i] = s_wcdot[n] / ((sqrtf(s_wcss[n]) + EPSf) * s_sc[3]) * s_sc[0];
                mx = fmaxf(mx, sims[i]);
            }
            mx = wmaxr(mx);
            float es[4], ls = 0.f;
#pragma unroll
            for (int i = 0; i < 4; ++i) { es[i] = __expf(sims[i] - mx); ls += es[i]; }
            ls = wsum(ls);
            float ag = s_sc[1], wg = s_sc[2], inv = rcpf(ls), lw = 0.f;
#pragma unroll
            for (int i = 0; i < 4; ++i) {
                int n = lane * 4 + i;
                float alloc = (1.f - uu[i]) * s_cp[rk[i]];
                float wwn = wg * (ag * alloc + (1.f - ag) * es[i] * inv);
                s_ww[n] = wwn; lw += wwn;
                s_wwh2[n] = pkh(wwn, wwn);
                s_tmh2[n] = pkh(1.f - wwn, 1.f - wwn);
            }
            lw = wsum(lw);
            if (lane == 0) s_red[0] = lw;
        }
        __syncthreads();  // B9

        // ---- P7: link col pass (8 waves; pk-fp16 update + perm bwd, chunk-prefetch)
        //      || mem RMW (8 waves) ----
        if (tid < 512) {
            int kc = tid >> 7, p = tid & 127;
            int c0 = 2 * p, c1 = c0 + 1;
            __half2 wwcp = pkh(s_ww[c0], s_ww[c1]);
            __half2 ptp  = pkh(s_prec[c0], s_prec[c1]);
            float acc[8] = {0,0,0,0,0,0,0,0};
            int kbase = kc * 64;
            __half2 lv[8];
#pragma unroll
            for (int u = 0; u < 8; ++u) lv[u] = lread((kbase + u) * LROW + p);
#pragma unroll 1
            for (int k0 = kbase; k0 < kbase + 64; k0 += 8) {
                // prefetch next chunk's link words (disjoint k-range; hides ds latency)
                __half2 lvn[8];
                if (k0 + 8 < kbase + 64) {
#pragma unroll
                    for (int u = 0; u < 8; ++u) lvn[u] = lread((k0 + 8 + u) * LROW + p);
                }
                __half2 tm[8], wk[8];
                *(float4*)&tm[0] = *(const float4*)(s_tmh2 + k0);
                *(float4*)&tm[4] = *(const float4*)(s_tmh2 + k0 + 4);
                *(float4*)&wk[0] = *(const float4*)(s_wwh2 + k0);
                *(float4*)&wk[4] = *(const float4*)(s_wwh2 + k0 + 4);
                __half2 ln[8];
#pragma unroll
                for (int u = 0; u < 8; ++u)
                    ln[u] = __hfma2(__hsub2(tm[u], wwcp), lv[u], __hmul2(wk[u], ptp));
#pragma unroll
                for (int u = 0; u < 8; ++u)
                    lwrite((k0 + u) * LROW + p, ln[u]);
                int kp0 = k0 >> 1;
                __half2 l0p[4], l1p[4];
#pragma unroll
                for (int i = 0; i < 4; ++i) {
                    unsigned ua = *(unsigned*)&ln[2*i], ub = *(unsigned*)&ln[2*i+1];
                    unsigned r0 = __builtin_amdgcn_perm(ub, ua, 0x05040100u);
                    unsigned r1 = __builtin_amdgcn_perm(ub, ua, 0x07060302u);
                    l0p[i] = *(__half2*)&r0; l1p[i] = *(__half2*)&r1;
                }
#pragma unroll
                for (int r = 0; r < 4; ++r) {
                    __half2 rp[4];
                    *(float4*)rp = *(const float4*)(s_rwh + r * RWS + kp0);
#pragma unroll
                    for (int i = 0; i < 4; ++i) {
                        acc[r]     = fdot2(l0p[i], rp[i], acc[r]);
                        acc[4 + r] = fdot2(l1p[i], rp[i], acc[4 + r]);
                    }
                }
                if (k0 + 8 < kbase + 64) {
#pragma unroll
                    for (int u = 0; u < 8; ++u) lv[u] = lvn[u];
                }
            }
            // diagonal fix (same-thread RAW only)
            if ((c0 >> 6) == kc) {
                __half2 d0 = lread(c0 * LROW + p);
                __half2 d1 = lread(c1 * LROW + p);
                float dl0 = __half2float(__low2half(d0));
                float dl1 = __half2float(__high2half(d1));
                unsigned u0 = *(unsigned*)&d0; u0 &= 0xFFFF0000u;
                unsigned u1 = *(unsigned*)&d1; u1 &= 0x0000FFFFu;
                lwrite(c0 * LROW + p, *(__half2*)&u0);
                lwrite(c1 * LROW + p, *(__half2*)&u1);
#pragma unroll
                for (int r = 0; r < 4; ++r) {
                    acc[r]     = fmaf(-dl0, s_rw[c0*4 + r], acc[r]);
                    acc[4 + r] = fmaf(-dl1, s_rw[c1*4 + r], acc[4 + r]);
                }
            }
            __half2* bp = (__half2*)scrh + (kc * 128 + p) * 4;
            bp[0] = pkh(acc[0], acc[1]);
            bp[1] = pkh(acc[2], acc[3]);
            bp[2] = pkh(acc[4], acc[5]);
            bp[3] = pkh(acc[6], acc[7]);
        } else {
            int t0 = tid - 512;
#pragma unroll 1
            for (int jb = 0; jb < 2; ++jb) {
                __half2 mv[8];
#pragma unroll
                for (int j = 0; j < 8; ++j) mv[j] = memh2[t0 + (jb * 8 + j) * 512];
#pragma unroll
                for (int j = 0; j < 8; ++j) {
                    int i2 = t0 + (jb * 8 + j) * 512;
                    int w = i2 >> 7, n2 = i2 & 127;
                    float er = s_er[w];
                    float wvv = s_z[389 + w];
                    float2 mf = __half22float2(mv[j]);
                    float wa = s_ww[2*n2], wb = s_ww[2*n2 + 1];
                    mf.x = mf.x * (1.f - wa * er) + wa * wvv;
                    mf.y = mf.y * (1.f - wb * er) + wb * wvv;
                    __half2 hv = __floats2half2_rn(mf.x, mf.y);
                    memh2[i2] = hv;
                    int wb2 = (w >> 1) * 512 + 4 * n2 + (w & 1);
                    memWh[wb2]     = __low2half(hv);
                    memWh[wb2 + 2] = __high2half(hv);
                }
            }
        }
        __syncthreads();  // B10

        // ---- P8: fwd row pass (b64 row reads, unroll 2) + prec update ----
        {
            int q = tid >> 8, n8 = tid & 255;
            float f[4] = {0.f, 0.f, 0.f, 0.f};
            int base = n8 * LROW + q * 32;   // even (LROW=130)
#pragma unroll 2
            for (int j0 = 0; j0 < 32; j0 += 8) {
                __half2 lv[8];
                float2 a0 = lread2(base + j0);
                float2 a1 = lread2(base + j0 + 2);
                float2 a2 = lread2(base + j0 + 4);
                float2 a3 = lread2(base + j0 + 6);
                *(float2*)&lv[0] = a0; *(float2*)&lv[2] = a1;
                *(float2*)&lv[4] = a2; *(float2*)&lv[6] = a3;
#pragma unroll
                for (int r = 0; r < 4; ++r) {
                    __half2 rp[8];
                    *(float4*)&rp[0] = *(const float4*)(s_rwh + r * RWS + q * 32 + j0);
                    *(float4*)&rp[4] = *(const float4*)(s_rwh + r * RWS + q * 32 + j0 + 4);
#pragma unroll
                    for (int u = 0; u < 8; ++u) f[r] = fdot2(lv[u], rp[u], f[r]);
                }
            }
            __half2* fp2 = (__half2*)(scrh + 4096) + (q * 256 + n8) * 2;
            fp2[0] = pkh(f[0], f[1]);
            fp2[1] = pkh(f[2], f[3]);
            if (q == 0) s_prec[n8] = (1.f - s_red[0]) * s_prec[n8] + s_ww[n8];
        }
        __syncthreads();  // B11

        // ---- P9: rc sim via memW (32 loads up-front) + bwd/fwd reduce ----
        int rr = tid >> 8, n8c = tid & 255;
        float bwv = 0.f, fwv = 0.f, e_rc = 0.f;
        {
            // issue all 32 memW column loads first; LDS sums run while in flight
            const __half2* mW = memW2 + n8c;
            __half2 mva[16], mvb[16];
#pragma unroll
            for (int u = 0; u < 16; ++u) mva[u] = mW[u * 256];
#pragma unroll
            for (int u = 0; u < 16; ++u) mvb[u] = mW[(16 + u) * 256];
#pragma unroll
            for (int kc = 0; kc < 4; ++kc)
                bwv += __half2float(scrh[(kc * 128 + (n8c >> 1)) * 8 + (n8c & 1) * 4 + rr]);
#pragma unroll
            for (int qq = 0; qq < 4; ++qq)
                fwv += __half2float(scrh[4096 + (qq * 256 + n8c) * 4 + rr]);
            const __half2* kh = s_keyh + rr * 32;
            float ssv = 0.f, dv = 0.f;
            {
                __half2 kv[16];
                *(float4*)&kv[0]  = *(const float4*)(kh);
                *(float4*)&kv[4]  = *(const float4*)(kh + 4);
                *(float4*)&kv[8]  = *(const float4*)(kh + 8);
                *(float4*)&kv[12] = *(const float4*)(kh + 12);
#pragma unroll
                for (int u = 0; u < 16; ++u) {
                    ssv = fdot2(mva[u], mva[u], ssv);
                    dv  = fdot2(mva[u], kv[u], dv);
                }
            }
            {
                __half2 kv[16];
                *(float4*)&kv[0]  = *(const float4*)(kh + 16);
                *(float4*)&kv[4]  = *(const float4*)(kh + 20);
                *(float4*)&kv[8]  = *(const float4*)(kh + 24);
                *(float4*)&kv[12] = *(const float4*)(kh + 28);
#pragma unroll
                for (int u = 0; u < 16; ++u) {
                    ssv = fdot2(mvb[u], mvb[u], ssv);
                    dv  = fdot2(mvb[u], kv[u], dv);
                }
            }
            float sim = dv / ((sqrtf(ssv) + EPSf) * s_knorm[rr]) * s_rstr[rr];
            e_rc = __expf(sim);      // |sim| small (strength-scaled cosine)
            float s = wsum(e_rc);
            if (lane == 0) s_red[16 + wv] = s;
        }
        __syncthreads();  // B12
        {
            float sm = (s_red[16+rr*4+0] + s_red[16+rr*4+1]) + (s_red[16+rr*4+2] + s_red[16+rr*4+3]);
            float rc = e_rc * rcpf(sm);
            float v = bwv * s_rmode[0*4+rr] + rc * s_rmode[1*4+rr] + fwv * s_rmode[2*4+rr];
            s_rw[n8c*4 + rr] = v;
            float pv = __shfl_xor(v, 1, 64);
            if ((n8c & 1) == 0) s_rwh[rr * RWS + (n8c >> 1)] = pkh(v, pv);
        }
        __syncthreads();  // B13

        // ---- P12: rvec, in-wave reduce -> ctrl pairs + next-x staging ----
        {
            int o = (wv << 4) + (lane & 15), kc = lane >> 4;
            int w = o >> 2, r = o & 3;
            const __half2* mw2 = (const __half2*)(memh + w * 256 + kc * 64);
            const __half2* rw2 = s_rwh + r * RWS + kc * 32;
            float a = 0.f;
#pragma unroll
            for (int c = 0; c < 8; ++c) {
                __half2 mv[4], rv[4];
                *(float4*)mv = *(const float4*)(mw2 + c * 4);
                *(float4*)rv = *(const float4*)(rw2 + c * 4);
#pragma unroll
                for (int u = 0; u < 4; ++u) a = fdot2(mv[u], rv[u], a);
            }
            a += __shfl_xor(a, 16, 64);
            a += __shfl_xor(a, 32, 64);
            if (lane < 16) {
                float pv = __shfl_xor(a, 1, 64);
                if ((lane & 1) == 0) s_ctrlh[32 + (o >> 1)] = pkh(a, pv);
            }
            if (wv < 2 && lane >= 48 && t + 1 < Tt) {
                int i = (wv << 4) + (lane - 48);
                float2 xv = *(const float2*)&x[((t + 1) * Bb + b) * INd + 2 * i];
                s_ctrlh[i] = pkh(xv.x, xv.y);
            }
        }
        __syncthreads();  // B15

        // ---- P14: out GEMV, in-wave 16-lane reduce -> direct global write ----
        {
            int o = (wv << 2) + (lane & 3), c = lane >> 2;
            const __half2* wsrc = (c < 8) ? (wp + WOUTOFF + o * 4 + c * 1024)
                                          : (wp + WMEMOFF + o * 4 + (c - 8) * 1024);
            const __half2* vsrc = (c < 8) ? (s_nnh + c * 16)
                                          : (s_ctrlh + 32 + (c - 8) * 16);
            float a = gemv_part(wsrc, 256, 16, vsrc);
            a += __shfl_xor(a, 4, 64);
            a += __shfl_xor(a, 8, 64);
            a += __shfl_xor(a, 16, 64);
            a += __shfl_xor(a, 32, 64);
            if (lane < 4) out[(t * Bb + b) * OUTd + o] = a;
        }
        // no loop-top barrier: P14 reads s_nnh/ctrl[32..) only; next P1 writes s_hh
        // (disjoint); ctrl stable since B15. First-iteration covered by entry barrier.
    }
}

extern "C" void kernel_launch(void* const* d_in, const int* in_sizes, int n_in,
                              void* d_out, int out_size, void* d_ws, size_t ws_size,
                              hipStream_t stream) {
    const float* x    = (const float*)d_in[0];
    const float* W1   = (const float*)d_in[1];
    const float* b1   = (const float*)d_in[2];
    const float* W2   = (const float*)d_in[3];
    const float* b2   = (const float*)d_in[4];
    const float* Wif  = (const float*)d_in[5];
    const float* bif  = (const float*)d_in[6];
    const float* Wout = (const float*)d_in[7];
    const float* Wmem = (const float*)d_in[8];
    float* out = (float*)d_out;

    // ws: [0, 601600) packed half2 weights; [601600, +512KB) mem fp16 [w][n];
    // then memW [w2][n] pair copy (512KB); then fallback link.
    char* ws = (char*)d_ws;
    __half2* wp    = (__half2*)ws;
    __half*  memg  = (__half*)(ws + 601600);
    __half2* memWg = (__half2*)(ws + 601600 + 524288);
    __half2* linkg = (__half2*)(ws + 601600 + 524288 + 524288);

    convert_weights<<<dim3((WTOT + 255) / 256), dim3(256), 0, stream>>>(W1, W2, Wif, Wout, Wmem, wp);

    hipError_t rc = hipFuncSetAttribute(
        reinterpret_cast<const void*>(&dnc_kernel<true>),
        hipFuncAttributeMaxDynamicSharedMemorySize, SMEM_MAIN);
    if (rc == hipSuccess) {
        dnc_kernel<true><<<dim3(Bb), dim3(1024), SMEM_MAIN, stream>>>(
            x, b1, b2, bif, wp, memg, memWg, linkg, out);
    } else {
        dnc_kernel<false><<<dim3(Bb), dim3(1024), SMEM_FB, stream>>>(
            x, b1, b2, bif, wp, memg, memWg, linkg, out);
    }
}

// Round 12
// 1673.410 us; speedup vs baseline: 1.3816x; 1.3816x over previous
//
#include <hip/hip_runtime.h>
#include <hip/hip_fp16.h>
#include <math.h>

#define Tt 64
#define Bb 16
#define Nn 256
#define Ww 64
#define Rr 4
#define INd 64
#define OUTd 64
#define IFS 471
#define EPSf 1e-6f

// packed half2 weight layout: quad-of-k2 per column, wave-coalesced.
#define W1OFF   0        // K2=160, Ncol=256 -> 40960
#define W2OFF   40960    // K2=128, Ncol=256 -> 32768
#define WIFOFF  73728    // K2=128, Ncol=471 -> 60288
#define WOUTOFF 134016   // K2=128, Ncol=64  -> 8192
#define WMEMOFF 142208   // K2=128, Ncol=64  -> 8192
#define WTOT    150400

// link: 256 rows x 130 dwords (even row stride -> b64 row reads in P8)
#define LROW    130
#define LINKB   (256 * LROW * 4)     // 133120 B
#define SCRB    16384                // 4096 floats / 8192 halfs
#define FIXF    3456
#define SMEM_MAIN (LINKB + SCRB + FIXF * 4)   // 163328 <= 163840
#define SMEM_FB   (SCRB + FIXF * 4)

// s_rwh padded r-stride: 132 dwords (132%32=4 -> r-groups on disjoint banks)
#define RWS 132

typedef _Float16 h2v __attribute__((ext_vector_type(2)));
__device__ __forceinline__ float fdot2(__half2 a, __half2 b, float c) {
    return __builtin_amdgcn_fdot2(*(h2v*)&a, *(h2v*)&b, c, false);
}
__device__ __forceinline__ __half2 pkh(float a, float b) {
    auto r = __builtin_amdgcn_cvt_pkrtz(a, b);   // __fp16 ext_vector(2)
    return *(__half2*)&r;
}

__device__ __forceinline__ float rcpf(float x) {
#if __has_builtin(__builtin_amdgcn_rcpf)
    return __builtin_amdgcn_rcpf(x);
#else
    return 1.f / x;
#endif
}
// fast sigmoid/tanh via native v_exp + v_rcp (~1e-6 rel err, << fp16 pipeline noise)
__device__ __forceinline__ float sigm(float x) { return rcpf(1.f + __expf(-x)); }
__device__ __forceinline__ float tanh_fast(float x) {
    float xc = fminf(fmaxf(x, -15.f), 15.f);
    float e = __expf(2.f * xc);
    return (e - 1.f) * rcpf(e + 1.f);
}
__device__ __forceinline__ float oneplus_(float x) {
    return 1.f + fmaxf(x, 0.f) + log1pf(expf(-fabsf(x)));
}
__device__ __forceinline__ float wsum(float v) {
#pragma unroll
    for (int o = 32; o; o >>= 1) v += __shfl_xor(v, o, 64);
    return v;
}
__device__ __forceinline__ float wmaxr(float v) {
#pragma unroll
    for (int o = 32; o; o >>= 1) v = fmaxf(v, __shfl_xor(v, o, 64));
    return v;
}

// shared GEMV-partial body (R8 version: depth-1 rotation, proven no-spill,
// best steady 1612). wP = column base (wp + OFF + n*4), str = Ncol*4
// (half2 units per k8 block), iters in k2 units (multiple of 8, >= 16).
__device__ __attribute__((noinline)) float gemv_part(
    const __half2* __restrict__ wP, int str, int iters,
    const __half2* __restrict__ vin)
{
    float a[8] = {0.f,0.f,0.f,0.f,0.f,0.f,0.f,0.f};
    float4 h0 = *(const float4*)(wP);
    float4 h1 = *(const float4*)(wP + str);
#pragma unroll 1
    for (int j0 = 0; j0 < iters - 8; j0 += 8) {
        int k8n = (j0 >> 2) + 2;
        float4 n0 = *(const float4*)(wP + (size_t)k8n * str);
        float4 n1 = *(const float4*)(wP + (size_t)(k8n + 1) * str);
        float4 v0 = *(const float4*)(vin + j0);
        float4 v1 = *(const float4*)(vin + j0 + 4);
        const __half2* hh0 = (const __half2*)&h0;
        const __half2* hh1 = (const __half2*)&h1;
        const __half2* vv0 = (const __half2*)&v0;
        const __half2* vv1 = (const __half2*)&v1;
#pragma unroll
        for (int u = 0; u < 4; ++u) a[u]     = fdot2(hh0[u], vv0[u], a[u]);
#pragma unroll
        for (int u = 0; u < 4; ++u) a[4 + u] = fdot2(hh1[u], vv1[u], a[4 + u]);
        h0 = n0; h1 = n1;
    }
    {
        float4 v0 = *(const float4*)(vin + iters - 8);
        float4 v1 = *(const float4*)(vin + iters - 4);
        const __half2* hh0 = (const __half2*)&h0;
        const __half2* hh1 = (const __half2*)&h1;
        const __half2* vv0 = (const __half2*)&v0;
        const __half2* vv1 = (const __half2*)&v1;
#pragma unroll
        for (int u = 0; u < 4; ++u) a[u]     = fdot2(hh0[u], vv0[u], a[u]);
#pragma unroll
        for (int u = 0; u < 4; ++u) a[4 + u] = fdot2(hh1[u], vv1[u], a[4 + u]);
    }
    return ((a[0]+a[1])+(a[2]+a[3])) + ((a[4]+a[5])+(a[6]+a[7]));
}

// ---- converter: fp32 weights -> packed half2 quad layout ----
__global__ void convert_weights(const float* __restrict__ W1, const float* __restrict__ W2,
                                const float* __restrict__ Wif, const float* __restrict__ Wout,
                                const float* __restrict__ Wmem, __half2* __restrict__ wp) {
    int i = blockIdx.x * blockDim.x + threadIdx.x;
    if (i >= WTOT) return;
    float a, b;
    if (i < W2OFF) {
        int q = i & 3, s = i >> 2, n = s & 255, k2 = (s >> 8) * 4 + q;
        a = W1[(2*k2)*256+n];  b = W1[(2*k2+1)*256+n];
    } else if (i < WIFOFF) {
        int t = i - W2OFF;
        int q = t & 3, s = t >> 2, n = s & 255, k2 = (s >> 8) * 4 + q;
        a = W2[(2*k2)*256+n];  b = W2[(2*k2+1)*256+n];
    } else if (i < WOUTOFF) {
        int t = i - WIFOFF;
        int q = t & 3, s = t >> 2, o = s % IFS, k2 = (s / IFS) * 4 + q;
        a = Wif[(2*k2)*IFS+o]; b = Wif[(2*k2+1)*IFS+o];
    } else if (i < WMEMOFF) {
        int t = i - WOUTOFF;
        int q = t & 3, s = t >> 2, n = s & 63, k2 = (s >> 6) * 4 + q;
        a = Wout[(2*k2)*64+n]; b = Wout[(2*k2+1)*64+n];
    } else {
        int t = i - WMEMOFF;
        int q = t & 3, s = t >> 2, n = s & 63, k2 = (s >> 6) * 4 + q;
        a = Wmem[(2*k2)*64+n]; b = Wmem[(2*k2+1)*64+n];
    }
    wp[i] = __floats2half2_rn(a, b);
}

template <bool LLINK>
__global__ __launch_bounds__(1024, 4) void dnc_kernel(
    // 2nd arg = 4 waves/EU = 16 waves/CU = 1 block/CU (LDS caps us there anyway)
    // -> VGPR budget 128 instead of the default-2-blocks cap of 64.
    const float* __restrict__ x, const float* __restrict__ b1,
    const float* __restrict__ b2, const float* __restrict__ bif,
    const __half2* __restrict__ wp,
    __half* __restrict__ memg,      // per batch 64*256 halves, [w][n]
    __half2* __restrict__ memWg,    // per batch 32*256 dwords, [w2][n]
    __half2* __restrict__ linkg,    // fallback link
    float* __restrict__ out)
{
    extern __shared__ __align__(16) char smem[];
    const int b = blockIdx.x;
    const int tid = threadIdx.x;
    const int lane = tid & 63;
    const int wv = tid >> 6;

    __half2* l2p = (__half2*)smem;
    __half2* gl2 = linkg + (size_t)b * (256 * LROW);
    float* scr   = (float*)(smem + (LLINK ? LINKB : 0));
    __half* scrh = (__half*)scr;
    float* fx    = (float*)((char*)scr + SCRB);

    float*   s_rw    = fx + 0;                    // 1024 [n][r] fp32
    __half2* s_ctrlh = (__half2*)(fx + 1024);     // 160
    __half2* s_hh    = (__half2*)(fx + 1184);     // 128
    __half2* s_nnh   = (__half2*)(fx + 1312);     // 128
    __half2* s_rwh   = (__half2*)(fx + 1440);     // 528 = [r][RWS n-pairs]
    float* s_z     = fx + 1968;   // 472
    float* s_usage = fx + 2440;   // 256
    float* s_ww    = fx + 2696;   // 256
    float* s_prec  = fx + 2952;   // 256
    float* s_knorm = fx + 3208;   // 4
    float* s_rstr  = fx + 3212;   // 4
    float* s_rmode = fx + 3216;   // 12
    float* s_sc    = fx + 3228;   // 4
    float* s_red   = fx + 3232;   // 32 ([0]=lw, [8..12)=fg, [16..32)=rc sums)
    float* s_er    = fx + 3264;   // 64 (erase gates)
    __half2* s_keyh = (__half2*)(fx + 3328);      // 128 [r][32 w2] -> 3456 = FIXF
    float* s_srt   = scr + 1024;  // 256 (mega only, B8..B9)
    float* s_cp    = scr + 1280;  // 256 (mega only, B8..B9)
    __half2* s_keyw2 = (__half2*)(scr + 1280);    // 32 write-key pairs (B6..B7)
    float* s_wcdot = scr + 1536;  // 256 (B7..B9)
    float* s_wcss  = scr + 1792;  // 256 (B7..B9)
    __half2* s_wwh2 = (__half2*)(scr + 2048);     // 256 dup (ww,ww)   (B9..B10)
    __half2* s_tmh2 = (__half2*)(scr + 2304);     // 256 dup (1-ww,1-ww)
    unsigned* s_keyu = (unsigned*)(scr + 2560);   // 256 u64 rank keys (B7..B8)

    __half*  memh  = memg + (size_t)b * (Ww * Nn);
    __half2* memh2 = (__half2*)memh;
    __half2* memW2 = memWg + (size_t)b * (32 * 256);
    __half*  memWh = (__half*)memW2;

    auto lread = [&](int idx) -> __half2 {
        if constexpr (LLINK) return l2p[idx]; else return gl2[idx];
    };
    auto lwrite = [&](int idx, __half2 v) {
        if constexpr (LLINK) l2p[idx] = v; else gl2[idx] = v;
    };
    auto lread2 = [&](int idx) -> float2 {   // idx even: half2[idx], half2[idx+1]
        if constexpr (LLINK) return *(const float2*)(l2p + idx);
        else return *(const float2*)(gl2 + idx);
    };

    // ---- init (ws/LDS poisoned before every launch) ----
    {
        __half2 z2 = pkh(0.f, 0.f);
#pragma unroll 1
        for (int i = tid; i < 256 * LROW; i += 1024) lwrite(i, z2);
        __half2 e2 = __floats2half2_rn(EPSf, EPSf);
#pragma unroll 1
        for (int j = 0; j < 8; ++j) { memh2[tid + j * 1024] = e2; memW2[tid + j * 1024] = e2; }
        if (tid < 528) s_rwh[tid] = z2;
        if (tid < 32) {
            float2 xv = *(const float2*)&x[b * INd + 2 * tid];
            s_ctrlh[tid] = pkh(xv.x, xv.y);
        } else if (tid < 160) s_ctrlh[tid] = z2;
    }
    if (tid < 256) {
        s_usage[tid] = 0.f; s_ww[tid] = 0.f; s_prec[tid] = 0.f;
        s_rw[tid*4+0] = 0.f; s_rw[tid*4+1] = 0.f; s_rw[tid*4+2] = 0.f; s_rw[tid*4+3] = 0.f;
    }
    __syncthreads();   // entry barrier (loop-top barrier removed)

#pragma unroll 1
    for (int t = 0; t < Tt; ++t) {
        // ---- P1: GEMV1, in-wave reduce + tanh -> s_hh ----
        {
            int o = (wv << 4) + (lane & 15), kc = lane >> 4;
            float a = gemv_part(wp + W1OFF + o * 4 + kc * 10240, 1024, 40,
                                s_ctrlh + kc * 40);
            a += __shfl_xor(a, 16, 64);
            a += __shfl_xor(a, 32, 64);
            if (lane < 16) {
                float v = tanh_fast(b1[o] + a);
                float pv = __shfl_xor(v, 1, 64);
                if ((lane & 1) == 0) s_hh[o >> 1] = pkh(v, pv);
            }
        }
        __syncthreads();  // B2

        // ---- P2: GEMV2, in-wave reduce + tanh -> s_nnh ----
        {
            int o = (wv << 4) + (lane & 15), kc = lane >> 4;
            float a = gemv_part(wp + W2OFF + o * 4 + kc * 8192, 1024, 32,
                                s_hh + kc * 32);
            a += __shfl_xor(a, 16, 64);
            a += __shfl_xor(a, 32, 64);
            if (lane < 16) {
                float v = tanh_fast(b2[o] + a);
                float pv = __shfl_xor(v, 1, 64);
                if ((lane & 1) == 0) s_nnh[o >> 1] = pkh(v, pv);
            }
        }
        __syncthreads();  // B4

        // ---- P3: GEMV3, in-wave reduce -> s_z + packed keys + free gates ----
        {
            int o = (wv << 5) + (lane & 31);
            int kc = lane >> 5;
            float a = 0.f;
            if (o < IFS)
                a = gemv_part(wp + WIFOFF + o * 4 + kc * 30144, 1884, 64,
                              s_nnh + kc * 64);
            a += __shfl_xor(a, 32, 64);
            if (lane < 32 && o < IFS) {
                float v = bif[o] + a;
                s_z[o] = v;
                float pv1 = __shfl_xor(v, 1, 64);
                float pv4 = __shfl_xor(v, 4, 64);
                if (o < 256) {
                    if ((o & 4) == 0)           // w even
                        s_keyh[(o & 3) * 32 + (o >> 3)] = pkh(v, pv4);
                } else if (o >= 260 && o < 324) {
                    if ((o & 1) == 0)
                        s_keyw2[(o - 260) >> 1] = pkh(v, pv1);
                } else if (o >= 453 && o < 457) {
                    s_red[8 + (o - 453)] = sigm(v);   // free gates, once
                }
            }
        }
        __syncthreads();  // B6

        // ---- P4: scalars + usage/keys + wc dot/ss (merged wave roles) ----
        if (wv < 4) {
            float vz = s_z[lane * 4 + wv];
            float s = wsum(vz * vz);
            if (lane == 0) s_knorm[wv] = sqrtf(s) + EPSf;
        } else if (wv == 4) {
            float vz = s_z[260 + lane];
            float s = wsum(vz * vz);
            if (lane == 0) s_sc[3] = sqrtf(s) + EPSf;
        } else if (wv == 5) {
            if (lane < 4) s_rstr[lane] = oneplus_(s_z[256 + lane]);
            else if (lane >= 8 && lane < 12) {
                int r = lane - 8;
                float a = s_z[459+r], bm = s_z[463+r], c = s_z[467+r];
                float mx = fmaxf(a, fmaxf(bm, c));
                float ea = __expf(a-mx), eb = __expf(bm-mx), ec = __expf(c-mx);
                float inv = rcpf((ea+eb)+ec);
                s_rmode[0*4+r] = ea*inv; s_rmode[1*4+r] = eb*inv; s_rmode[2*4+r] = ec*inv;
            } else if (lane == 16) s_sc[0] = oneplus_(s_z[324]);
            else if (lane == 17) s_sc[1] = sigm(s_z[457]);
            else if (lane == 18) s_sc[2] = sigm(s_z[458]);
        } else if (wv == 6) {
            s_er[lane] = sigm(s_z[325 + lane]);   // erase gates, once per step
        } else if (wv >= 8 && wv < 12) {
            int n = tid - 512;
            float4 rw4 = *(const float4*)&s_rw[n*4];
            float4 fg4 = *(const float4*)&s_red[8];
            float ret = (1.f - fg4.x*rw4.x) * (1.f - fg4.y*rw4.y)
                      * (1.f - fg4.z*rw4.z) * (1.f - fg4.w*rw4.w);
            float u = s_usage[n], wwo = s_ww[n];
            float unew = (u + wwo - u * wwo) * ret;
            s_usage[n] = unew;
            // u64 sort key: usage>=0 -> IEEE bits order-monotonic; key = bits*256 + n
            unsigned ub = __float_as_uint(unew);
            s_keyu[2*n]     = (ub << 8) | (unsigned)n;
            s_keyu[2*n + 1] = ub >> 24;
        } else if (wv >= 12) {
            // wc dot/ss via memW (old mem, coalesced dword columns, batched loads)
            int n = tid - 768;
            const __half2* mW = memW2 + n;
            float dot = 0.f, ssv = 0.f;
#pragma unroll 1
            for (int hf = 0; hf < 2; ++hf) {
                __half2 mv[16], kv[16];
#pragma unroll
                for (int u = 0; u < 16; ++u) mv[u] = mW[(hf * 16 + u) * 256];
                *(float4*)&kv[0]  = *(const float4*)(s_keyw2 + hf*16);
                *(float4*)&kv[4]  = *(const float4*)(s_keyw2 + hf*16 + 4);
                *(float4*)&kv[8]  = *(const float4*)(s_keyw2 + hf*16 + 8);
                *(float4*)&kv[12] = *(const float4*)(s_keyw2 + hf*16 + 12);
#pragma unroll
                for (int u = 0; u < 16; ++u) {
                    ssv = fdot2(mv[u], mv[u], ssv);
                    dot = fdot2(mv[u], kv[u], dot);
                }
            }
            s_wcdot[n] = dot; s_wcss[n] = ssv;
        }
        __syncthreads();  // B7

        // ---- P5: rank partials (u64 keys, broadcast b128 loads) ----
        {
            int q = tid >> 8, n = tid & 255;
            unsigned long long kn = *(const unsigned long long*)&s_keyu[2*n];
            int cnt = 0;
            const unsigned long long* kp = (const unsigned long long*)s_keyu;
            int j0 = q * 64;
#pragma unroll 8
            for (int j = j0; j < j0 + 64; j += 2) {
                ulonglong2 kk = *(const ulonglong2*)&kp[j];
                cnt += (kk.x < kn);
                cnt += (kk.y < kn);
            }
            scr[q * 256 + n] = (float)cnt;
        }
        __syncthreads();  // B8

        // ---- P6: mega (wave 0) ----
        if (wv == 0) {
            int rk[4]; float uu[4];
#pragma unroll
            for (int i = 0; i < 4; ++i) {
                int n = lane * 4 + i;
                float c = scr[n] + scr[256+n] + scr[512+n] + scr[768+n];
                rk[i] = (int)(c + 0.5f);
                uu[i] = s_usage[n];
                s_srt[rk[i]] = uu[i];
            }
            float4 vs = ((const float4*)s_srt)[lane];
            float p1 = vs.x * vs.y, p2 = p1 * vs.z, tot = p2 * vs.w;
            float incl = tot;
#pragma unroll
            for (int off = 1; off < 64; off <<= 1) {
                float tv = __shfl_up(incl, off, 64);
                if (lane >= off) incl *= tv;
            }
            float excl = __shfl_up(incl, 1, 64);
            if (lane == 0) excl = 1.f;
            float4 o4v; o4v.x = excl; o4v.y = excl*vs.x; o4v.z = excl*p1; o4v.w = excl*p2;
            ((float4*)s_cp)[lane] = o4v;

            float sims[4], mx = -1e30f;
#pragma unroll
            for (int i = 0; i < 4; ++i) {
                int n = lane * 4 + i;
                sims[i] = s_wcdot[n] / ((sqrtf(s_wcss[n]) + EPSf) * s_sc[3]) * s_sc[0];
                mx = fmaxf(mx, sims[i]);
            }
            mx = wmaxr(mx);
            float es[4], ls = 0.f;
#pragma unroll
            for (int i = 0; i < 4; ++i) { es[i] = __expf(sims[i] - mx); ls += es[i]; }
            ls = wsum(ls);
            float ag = s_sc[1], wg = s_sc[2], inv = rcpf(ls), lw = 0.f;
#pragma unroll
            for (int i = 0; i < 4; ++i) {
                int n = lane * 4 + i;
                float alloc = (1.f - uu[i]) * s_cp[rk[i]];
                float wwn = wg * (ag * alloc + (1.f - ag) * es[i] * inv);
                s_ww[n] = wwn; lw += wwn;
                s_wwh2[n] = pkh(wwn, wwn);
                s_tmh2[n] = pkh(1.f - wwn, 1.f - wwn);
            }
            lw = wsum(lw);
            if (lane == 0) s_red[0] = lw;
        }
        __syncthreads();  // B9

        // ---- P7: link col pass (8 waves; pk-fp16 update + perm bwd) || mem RMW (8 waves) ----
        if (tid < 512) {
            int kc = tid >> 7, p = tid & 127;
            int c0 = 2 * p, c1 = c0 + 1;
            __half2 wwcp = pkh(s_ww[c0], s_ww[c1]);
            __half2 ptp  = pkh(s_prec[c0], s_prec[c1]);
            float acc[8] = {0,0,0,0,0,0,0,0};
            int kbase = kc * 64;
#pragma unroll 1
            for (int k0 = kbase; k0 < kbase + 64; k0 += 8) {
                __half2 lv[8], tm[8], wk[8];
#pragma unroll
                for (int u = 0; u < 8; ++u) lv[u] = lread((k0 + u) * LROW + p);
                *(float4*)&tm[0] = *(const float4*)(s_tmh2 + k0);
                *(float4*)&tm[4] = *(const float4*)(s_tmh2 + k0 + 4);
                *(float4*)&wk[0] = *(const float4*)(s_wwh2 + k0);
                *(float4*)&wk[4] = *(const float4*)(s_wwh2 + k0 + 4);
                __half2 ln[8];
#pragma unroll
                for (int u = 0; u < 8; ++u)
                    ln[u] = __hfma2(__hsub2(tm[u], wwcp), lv[u], __hmul2(wk[u], ptp));
#pragma unroll
                for (int u = 0; u < 8; ++u)
                    lwrite((k0 + u) * LROW + p, ln[u]);
                int kp0 = k0 >> 1;
                __half2 l0p[4], l1p[4];
#pragma unroll
                for (int i = 0; i < 4; ++i) {
                    unsigned ua = *(unsigned*)&ln[2*i], ub = *(unsigned*)&ln[2*i+1];
                    unsigned r0 = __builtin_amdgcn_perm(ub, ua, 0x05040100u);
                    unsigned r1 = __builtin_amdgcn_perm(ub, ua, 0x07060302u);
                    l0p[i] = *(__half2*)&r0; l1p[i] = *(__half2*)&r1;
                }
#pragma unroll
                for (int r = 0; r < 4; ++r) {
                    __half2 rp[4];
                    *(float4*)rp = *(const float4*)(s_rwh + r * RWS + kp0);
#pragma unroll
                    for (int i = 0; i < 4; ++i) {
                        acc[r]     = fdot2(l0p[i], rp[i], acc[r]);
                        acc[4 + r] = fdot2(l1p[i], rp[i], acc[4 + r]);
                    }
                }
            }
            // diagonal fix (same-thread RAW only)
            if ((c0 >> 6) == kc) {
                __half2 d0 = lread(c0 * LROW + p);
                __half2 d1 = lread(c1 * LROW + p);
                float dl0 = __half2float(__low2half(d0));
                float dl1 = __half2float(__high2half(d1));
                unsigned u0 = *(unsigned*)&d0; u0 &= 0xFFFF0000u;
                unsigned u1 = *(unsigned*)&d1; u1 &= 0x0000FFFFu;
                lwrite(c0 * LROW + p, *(__half2*)&u0);
                lwrite(c1 * LROW + p, *(__half2*)&u1);
#pragma unroll
                for (int r = 0; r < 4; ++r) {
                    acc[r]     = fmaf(-dl0, s_rw[c0*4 + r], acc[r]);
                    acc[4 + r] = fmaf(-dl1, s_rw[c1*4 + r], acc[4 + r]);
                }
            }
            __half2* bp = (__half2*)scrh + (kc * 128 + p) * 4;
            bp[0] = pkh(acc[0], acc[1]);
            bp[1] = pkh(acc[2], acc[3]);
            bp[2] = pkh(acc[4], acc[5]);
            bp[3] = pkh(acc[6], acc[7]);
        } else {
            int t0 = tid - 512;
#pragma unroll 1
            for (int jb = 0; jb < 2; ++jb) {
                __half2 mv[8];
#pragma unroll
                for (int j = 0; j < 8; ++j) mv[j] = memh2[t0 + (jb * 8 + j) * 512];
#pragma unroll
                for (int j = 0; j < 8; ++j) {
                    int i2 = t0 + (jb * 8 + j) * 512;
                    int w = i2 >> 7, n2 = i2 & 127;
                    float er = s_er[w];
                    float wvv = s_z[389 + w];
                    float2 mf = __half22float2(mv[j]);
                    float wa = s_ww[2*n2], wb = s_ww[2*n2 + 1];
                    mf.x = mf.x * (1.f - wa * er) + wa * wvv;
                    mf.y = mf.y * (1.f - wb * er) + wb * wvv;
                    __half2 hv = __floats2half2_rn(mf.x, mf.y);
                    memh2[i2] = hv;
                    int wb2 = (w >> 1) * 512 + 4 * n2 + (w & 1);
                    memWh[wb2]     = __low2half(hv);
                    memWh[wb2 + 2] = __high2half(hv);
                }
            }
        }
        __syncthreads();  // B10

        // ---- P8: fwd row pass (b64 row reads, fdot2) + prec update ----
        {
            int q = tid >> 8, n8 = tid & 255;
            float f[4] = {0.f, 0.f, 0.f, 0.f};
            int base = n8 * LROW + q * 32;   // even (LROW=130)
#pragma unroll 1
            for (int j0 = 0; j0 < 32; j0 += 8) {
                __half2 lv[8];
                float2 a0 = lread2(base + j0);
                float2 a1 = lread2(base + j0 + 2);
                float2 a2 = lread2(base + j0 + 4);
                float2 a3 = lread2(base + j0 + 6);
                *(float2*)&lv[0] = a0; *(float2*)&lv[2] = a1;
                *(float2*)&lv[4] = a2; *(float2*)&lv[6] = a3;
#pragma unroll
                for (int r = 0; r < 4; ++r) {
                    __half2 rp[8];
                    *(float4*)&rp[0] = *(const float4*)(s_rwh + r * RWS + q * 32 + j0);
                    *(float4*)&rp[4] = *(const float4*)(s_rwh + r * RWS + q * 32 + j0 + 4);
#pragma unroll
                    for (int u = 0; u < 8; ++u) f[r] = fdot2(lv[u], rp[u], f[r]);
                }
            }
            __half2* fp2 = (__half2*)(scrh + 4096) + (q * 256 + n8) * 2;
            fp2[0] = pkh(f[0], f[1]);
            fp2[1] = pkh(f[2], f[3]);
            if (q == 0) s_prec[n8] = (1.f - s_red[0]) * s_prec[n8] + s_ww[n8];
        }
        __syncthreads();  // B11

        // ---- P9: rc sim via memW (batched loads) + bwd/fwd reduce ----
        int rr = tid >> 8, n8c = tid & 255;
        float bwv = 0.f, fwv = 0.f, e_rc = 0.f;
        {
#pragma unroll
            for (int kc = 0; kc < 4; ++kc)
                bwv += __half2float(scrh[(kc * 128 + (n8c >> 1)) * 8 + (n8c & 1) * 4 + rr]);
#pragma unroll
            for (int qq = 0; qq < 4; ++qq)
                fwv += __half2float(scrh[4096 + (qq * 256 + n8c) * 4 + rr]);
            const __half2* mW = memW2 + n8c;
            const __half2* kh = s_keyh + rr * 32;
            float ssv = 0.f, dv = 0.f;
#pragma unroll 1
            for (int hf = 0; hf < 2; ++hf) {
                __half2 mv[16], kv[16];
#pragma unroll
                for (int u = 0; u < 16; ++u) mv[u] = mW[(hf * 16 + u) * 256];
                *(float4*)&kv[0]  = *(const float4*)(kh + hf*16);
                *(float4*)&kv[4]  = *(const float4*)(kh + hf*16 + 4);
                *(float4*)&kv[8]  = *(const float4*)(kh + hf*16 + 8);
                *(float4*)&kv[12] = *(const float4*)(kh + hf*16 + 12);
#pragma unroll
                for (int u = 0; u < 16; ++u) {
                    ssv = fdot2(mv[u], mv[u], ssv);
                    dv  = fdot2(mv[u], kv[u], dv);
                }
            }
            float sim = dv / ((sqrtf(ssv) + EPSf) * s_knorm[rr]) * s_rstr[rr];
            e_rc = __expf(sim);      // |sim| small (strength-scaled cosine)
            float s = wsum(e_rc);
            if (lane == 0) s_red[16 + wv] = s;
        }
        __syncthreads();  // B12
        {
            float sm = (s_red[16+rr*4+0] + s_red[16+rr*4+1]) + (s_red[16+rr*4+2] + s_red[16+rr*4+3]);
            float rc = e_rc * rcpf(sm);
            float v = bwv * s_rmode[0*4+rr] + rc * s_rmode[1*4+rr] + fwv * s_rmode[2*4+rr];
            s_rw[n8c*4 + rr] = v;
            float pv = __shfl_xor(v, 1, 64);
            if ((n8c & 1) == 0) s_rwh[rr * RWS + (n8c >> 1)] = pkh(v, pv);
        }
        __syncthreads();  // B13

        // ---- P12: rvec, in-wave reduce -> ctrl pairs + next-x staging ----
        {
            int o = (wv << 4) + (lane & 15), kc = lane >> 4;
            int w = o >> 2, r = o & 3;
            const __half2* mw2 = (const __half2*)(memh + w * 256 + kc * 64);
            const __half2* rw2 = s_rwh + r * RWS + kc * 32;
            float a = 0.f;
#pragma unroll
            for (int c = 0; c < 8; ++c) {
                __half2 mv[4], rv[4];
                *(float4*)mv = *(const float4*)(mw2 + c * 4);
                *(float4*)rv = *(const float4*)(rw2 + c * 4);
#pragma unroll
                for (int u = 0; u < 4; ++u) a = fdot2(mv[u], rv[u], a);
            }
            a += __shfl_xor(a, 16, 64);
            a += __shfl_xor(a, 32, 64);
            if (lane < 16) {
                float pv = __shfl_xor(a, 1, 64);
                if ((lane & 1) == 0) s_ctrlh[32 + (o >> 1)] = pkh(a, pv);
            }
            if (wv < 2 && lane >= 48 && t + 1 < Tt) {
                int i = (wv << 4) + (lane - 48);
                float2 xv = *(const float2*)&x[((t + 1) * Bb + b) * INd + 2 * i];
                s_ctrlh[i] = pkh(xv.x, xv.y);
            }
        }
        __syncthreads();  // B15

        // ---- P14: out GEMV, in-wave 16-lane reduce -> direct global write ----
        {
            int o = (wv << 2) + (lane & 3), c = lane >> 2;
            const __half2* wsrc = (c < 8) ? (wp + WOUTOFF + o * 4 + c * 1024)
                                          : (wp + WMEMOFF + o * 4 + (c - 8) * 1024);
            const __half2* vsrc = (c < 8) ? (s_nnh + c * 16)
                                          : (s_ctrlh + 32 + (c - 8) * 16);
            float a = gemv_part(wsrc, 256, 16, vsrc);
            a += __shfl_xor(a, 4, 64);
            a += __shfl_xor(a, 8, 64);
            a += __shfl_xor(a, 16, 64);
            a += __shfl_xor(a, 32, 64);
            if (lane < 4) out[(t * Bb + b) * OUTd + o] = a;
        }
        // no loop-top barrier: P14 reads s_nnh/ctrl[32..) only; next P1 writes s_hh
        // (disjoint); ctrl stable since B15. First-iteration covered by entry barrier.
    }
}

extern "C" void kernel_launch(void* const* d_in, const int* in_sizes, int n_in,
                              void* d_out, int out_size, void* d_ws, size_t ws_size,
                              hipStream_t stream) {
    const float* x    = (const float*)d_in[0];
    const float* W1   = (const float*)d_in[1];
    const float* b1   = (const float*)d_in[2];
    const float* W2   = (const float*)d_in[3];
    const float* b2   = (const float*)d_in[4];
    const float* Wif  = (const float*)d_in[5];
    const float* bif  = (const float*)d_in[6];
    const float* Wout = (const float*)d_in[7];
    const float* Wmem = (const float*)d_in[8];
    float* out = (float*)d_out;

    // ws: [0, 601600) packed half2 weights; [601600, +512KB) mem fp16 [w][n];
    // then memW [w2][n] pair copy (512KB); then fallback link.
    char* ws = (char*)d_ws;
    __half2* wp    = (__half2*)ws;
    __half*  memg  = (__half*)(ws + 601600);
    __half2* memWg = (__half2*)(ws + 601600 + 524288);
    __half2* linkg = (__half2*)(ws + 601600 + 524288 + 524288);

    convert_weights<<<dim3((WTOT + 255) / 256), dim3(256), 0, stream>>>(W1, W2, Wif, Wout, Wmem, wp);

    hipError_t rc = hipFuncSetAttribute(
        reinterpret_cast<const void*>(&dnc_kernel<true>),
        hipFuncAttributeMaxDynamicSharedMemorySize, SMEM_MAIN);
    if (rc == hipSuccess) {
        dnc_kernel<true><<<dim3(Bb), dim3(1024), SMEM_MAIN, stream>>>(
            x, b1, b2, bif, wp, memg, memWg, linkg, out);
    } else {
        dnc_kernel<false><<<dim3(Bb), dim3(1024), SMEM_FB, stream>>>(
            x, b1, b2, bif, wp, memg, memWg, linkg, out);
    }
}